// Round 7
// baseline (12.375 us; speedup 1.0000x reference)
//
#include <hip/hip_runtime.h>
#include <math.h>

#define NQ 9
#define QD 6
#define NBATCH 32

typedef int v2i __attribute__((ext_vector_type(2)));

__device__ __forceinline__ int   f2i(float x) { return __float_as_int(x); }
__device__ __forceinline__ float i2f(int x)   { return __int_as_float(x); }

__device__ __forceinline__ float bperm_f(int srcLane, float v) {
  return i2f(__builtin_amdgcn_ds_bpermute(srcLane << 2, f2i(v)));
}
__device__ __forceinline__ float rdlane_f(float v, int l) {
  return i2f(__builtin_amdgcn_readlane(f2i(v), l));
}
__device__ __forceinline__ float tanh_fast(float x) {
  const float e = __expf(2.0f * x);   // limits exact: inf->1, 0->-1
  return 1.0f - 2.0f / (e + 1.0f);
}

// cross-lane xor-by-MASK — r4-validated set ONLY (quad_perm, ds_swizzle, permlane32)
template <int MASK>
__device__ __forceinline__ float shx(float v, int lane) {
  if constexpr (MASK == 1) {        // quad_perm [1,0,3,2] — VALU DPP (validated r4)
    return i2f(__builtin_amdgcn_mov_dpp(f2i(v), 0xB1, 0xF, 0xF, true));
  } else if constexpr (MASK == 2) { // quad_perm [2,3,0,1] — VALU DPP (validated r4)
    return i2f(__builtin_amdgcn_mov_dpp(f2i(v), 0x4E, 0xF, 0xF, true));
  } else if constexpr (MASK == 4) { // ds_swizzle (validated r2/r4)
    return i2f(__builtin_amdgcn_ds_swizzle(f2i(v), 0x101F));
  } else if constexpr (MASK == 8) {
    return i2f(__builtin_amdgcn_ds_swizzle(f2i(v), 0x201F));
  } else if constexpr (MASK == 16) {
    return i2f(__builtin_amdgcn_ds_swizzle(f2i(v), 0x401F));
  } else {                          // MASK == 32 — permlane32_swap (validated r4)
    v2i r = __builtin_amdgcn_permlane32_swap(f2i(v), f2i(v), false, false);
    return i2f((lane & 32) ? r.x : r.y);
  }
}

// RY on a lane bit (MASK = 1<<bit)
template <int MASK>
__device__ __forceinline__ void ry_lane(float (&a)[8], float c, float s, int lane) {
  const float sgn = (lane & MASK) ? s : -s;
  float p[8];
  #pragma unroll
  for (int r = 0; r < 8; ++r) p[r] = shx<MASK>(a[r], lane);
  #pragma unroll
  for (int r = 0; r < 8; ++r) a[r] = c * a[r] + sgn * p[r];
}

// RY on a register bit RB
template <int RB>
__device__ __forceinline__ void ry_reg(float (&a)[8], float c, float s) {
  #pragma unroll
  for (int r = 0; r < 8; ++r) {
    if (!(r & (1 << RB))) {
      const int r1 = r | (1 << RB);
      const float a0 = a[r], a1 = a[r1];
      a[r]  = c * a0 - s * a1;
      a[r1] = s * a0 + c * a1;
    }
  }
}

// full 64-lane butterfly sum of N interleaved values (validated r4)
template <int N>
__device__ __forceinline__ void red64(float (&v)[N], int lane) {
  #pragma unroll
  for (int w = 0; w < N; ++w) v[w] += shx<1>(v[w], lane);
  #pragma unroll
  for (int w = 0; w < N; ++w) v[w] += shx<2>(v[w], lane);
  #pragma unroll
  for (int w = 0; w < N; ++w) v[w] += shx<4>(v[w], lane);
  #pragma unroll
  for (int w = 0; w < N; ++w) v[w] += shx<8>(v[w], lane);
  #pragma unroll
  for (int w = 0; w < N; ++w) v[w] += shx<16>(v[w], lane);
  #pragma unroll
  for (int w = 0; w < N; ++w) v[w] += shx<32>(v[w], lane);
}

__global__ __launch_bounds__(64) void qst_kernel(
    const float* __restrict__ x,       // [32,54]
    const float* __restrict__ pre_w,   // [9,54]
    const float* __restrict__ pre_b,   // [9]
    const float* __restrict__ qp,      // [54] = [6,9]
    const float* __restrict__ post_w,  // [9,9]
    const float* __restrict__ post_b,  // [9]
    float* __restrict__ out)           // [32,9]
{
  const int b = blockIdx.x;
  const int lane = (int)threadIdx.x;  // one wave per batch element

  // ---- circuit-weight trig, lane-parallel: lane i holds cos/sin(qp[i]/2) ----
  const float qv = (lane < 54) ? qp[lane] : 0.0f;
  const float qc = __cosf(qv * 0.5f);
  const float qs = __sinf(qv * 0.5f);

  // ---- pre-layer: 9 interleaved 64-lane reductions (r4-validated butterfly) ----
  const float xv = (lane < 54) ? x[b * 54 + lane] : 0.0f;
  float s9[NQ];
  #pragma unroll
  for (int w = 0; w < NQ; ++w) {
    const float pw = (lane < 54) ? pre_w[w * 54 + lane] : 0.0f;
    s9[w] = xv * pw;
  }
  red64<NQ>(s9, lane);
  float em[NQ], ep[NQ];   // c-s, c+s per wire (wave-uniform after butterfly)
  #pragma unroll
  for (int w = 0; w < NQ; ++w) {
    const float h = tanh_fast(s9[w] + pre_b[w]) * 0.78539816339744831f;  // theta/2
    const float c = __cosf(h), s = __sinf(h);
    em[w] = c - s;
    ep[w] = c + s;
  }

  // state: idx = lane*8 + r. wire w -> idx bit (8-w): w=0..5 -> lane bit (5-w); w=6,7,8 -> reg bit 2,1,0.
  // Input RY layer on the uniform H-state is SEPARABLE (product state):
  //   amp(idx) = 1/sqrt(512) * prod_w (bit_w ? (c_w+s_w) : (c_w-s_w))
  const float f0 = (lane & 32) ? ep[0] : em[0];
  const float f1 = (lane & 16) ? ep[1] : em[1];
  const float f2 = (lane &  8) ? ep[2] : em[2];
  const float f3 = (lane &  4) ? ep[3] : em[3];
  const float f4 = (lane &  2) ? ep[4] : em[4];
  const float f5 = (lane &  1) ? ep[5] : em[5];
  const float P  = 0.044194173824159216f * ((f0 * f1) * (f2 * f3)) * (f4 * f5);
  float a[8];
  #pragma unroll
  for (int r = 0; r < 8; ++r)
    a[r] = P * ((r & 4) ? ep[6] : em[6])
             * ((r & 2) ? ep[7] : em[7])
             * ((r & 1) ? ep[8] : em[8]);

  // ---- 6 depth iterations ----
  // Both CNOT layers fused into one gather: out[i] = in[T(i)], T linear over GF(2):
  //  srcLane = lane ^ ((lane>>1)&0x1F) ^ ((lane>>2)&0x05)   (same for all regs)
  //  srcReg  = s0(r) ^ (lane&1 ? 6 : 0), s0 = [0,1,3,2,6,7,5,4]
  const int srcLane = lane ^ ((lane >> 1) & 0x1F) ^ ((lane >> 2) & 0x05);
  #pragma unroll
  for (int k = 0; k < QD; ++k) {
    float u[8];
    #pragma unroll
    for (int r = 0; r < 8; ++r) u[r] = bperm_f(srcLane, a[r]);
    const bool L0 = lane & 1;
    a[0] = L0 ? u[6] : u[0];
    a[1] = L0 ? u[7] : u[1];
    a[2] = L0 ? u[5] : u[3];
    a[3] = L0 ? u[4] : u[2];
    a[4] = L0 ? u[0] : u[6];
    a[5] = L0 ? u[1] : u[7];
    a[6] = L0 ? u[3] : u[5];
    a[7] = L0 ? u[2] : u[4];

    // weight RY layer: broadcast cos/sin from lane k*9+w
    ry_lane<32>(a, rdlane_f(qc, k * NQ + 0), rdlane_f(qs, k * NQ + 0), lane);
    ry_lane<16>(a, rdlane_f(qc, k * NQ + 1), rdlane_f(qs, k * NQ + 1), lane);
    ry_lane< 8>(a, rdlane_f(qc, k * NQ + 2), rdlane_f(qs, k * NQ + 2), lane);
    ry_lane< 4>(a, rdlane_f(qc, k * NQ + 3), rdlane_f(qs, k * NQ + 3), lane);
    ry_lane< 2>(a, rdlane_f(qc, k * NQ + 4), rdlane_f(qs, k * NQ + 4), lane);
    ry_lane< 1>(a, rdlane_f(qc, k * NQ + 5), rdlane_f(qs, k * NQ + 5), lane);
    ry_reg<2>(a, rdlane_f(qc, k * NQ + 6), rdlane_f(qs, k * NQ + 6));
    ry_reg<1>(a, rdlane_f(qc, k * NQ + 7), rdlane_f(qs, k * NQ + 7));
    ry_reg<0>(a, rdlane_f(qc, k * NQ + 8), rdlane_f(qs, k * NQ + 8));
  }

  // ---- expectations <Z_w> ----
  float sq[8];
  #pragma unroll
  for (int r = 0; r < 8; ++r) sq[r] = a[r] * a[r];
  const float S  = ((sq[0] + sq[1]) + (sq[2] + sq[3])) + ((sq[4] + sq[5]) + (sq[6] + sq[7]));
  const float T2 = ((sq[0] + sq[1]) + (sq[2] + sq[3])) - ((sq[4] + sq[5]) + (sq[6] + sq[7]));
  const float T1 = ((sq[0] + sq[1]) + (sq[4] + sq[5])) - ((sq[2] + sq[3]) + (sq[6] + sq[7]));
  const float T0 = ((sq[0] + sq[2]) + (sq[4] + sq[6])) - ((sq[1] + sq[3]) + (sq[5] + sq[7]));

  float q[NQ];
  #pragma unroll
  for (int w = 0; w < 6; ++w)
    q[w] = ((lane >> (5 - w)) & 1) ? -S : S;
  q[6] = T2; q[7] = T1; q[8] = T0;

  red64<NQ>(q, lane);   // r4-validated butterfly; total in every lane

  // ---- post layer ----
  if (lane < NQ) {
    float acc = post_b[lane];
    #pragma unroll
    for (int w = 0; w < NQ; ++w) acc += q[w] * post_w[lane * NQ + w];
    out[b * NQ + lane] = acc;
  }
}

extern "C" void kernel_launch(void* const* d_in, const int* in_sizes, int n_in,
                              void* d_out, int out_size, void* d_ws, size_t ws_size,
                              hipStream_t stream) {
  qst_kernel<<<NBATCH, 64, 0, stream>>>(
      (const float*)d_in[0], (const float*)d_in[1], (const float*)d_in[2],
      (const float*)d_in[3], (const float*)d_in[4], (const float*)d_in[5],
      (float*)d_out);
}

// Round 8
// 11.143 us; speedup vs baseline: 1.1106x; 1.1106x over previous
//
#include <hip/hip_runtime.h>
#include <math.h>

#define NQ 9
#define QD 6
#define NBATCH 32

typedef int v2i __attribute__((ext_vector_type(2)));

__device__ __forceinline__ int   f2i(float x) { return __float_as_int(x); }
__device__ __forceinline__ float i2f(int x)   { return __int_as_float(x); }

__device__ __forceinline__ float bperm_f(int srcLane, float v) {
  return i2f(__builtin_amdgcn_ds_bpermute(srcLane << 2, f2i(v)));
}
__device__ __forceinline__ float rdlane_f(float v, int l) {
  return i2f(__builtin_amdgcn_readlane(f2i(v), l));
}
__device__ __forceinline__ float tanh_fast(float x) {
  const float e = __expf(2.0f * x);   // limits exact: inf->1, 0->-1
  return 1.0f - 2.0f / (e + 1.0f);
}

// cross-lane xor-by-MASK — r4-validated set + permlane16_swap (sibling of validated 32-swap)
template <int MASK>
__device__ __forceinline__ float shx(float v, int lane) {
  if constexpr (MASK == 1) {        // quad_perm [1,0,3,2] — VALU DPP (validated r4)
    return i2f(__builtin_amdgcn_mov_dpp(f2i(v), 0xB1, 0xF, 0xF, true));
  } else if constexpr (MASK == 2) { // quad_perm [2,3,0,1] — VALU DPP (validated r4)
    return i2f(__builtin_amdgcn_mov_dpp(f2i(v), 0x4E, 0xF, 0xF, true));
  } else if constexpr (MASK == 4) { // ds_swizzle (validated r2/r4)
    return i2f(__builtin_amdgcn_ds_swizzle(f2i(v), 0x101F));
  } else if constexpr (MASK == 8) { // ds_swizzle (validated r2/r4)
    return i2f(__builtin_amdgcn_ds_swizzle(f2i(v), 0x201F));
  } else if constexpr (MASK == 16) {
    // permlane16_swap: swap odd 16-rows of vdst with even 16-rows of vsrc.
    // Same half-select pattern as the r4-validated permlane32_swap.
    v2i r = __builtin_amdgcn_permlane16_swap(f2i(v), f2i(v), false, false);
    return i2f((lane & 16) ? r.x : r.y);
  } else {                          // MASK == 32 — permlane32_swap (validated r4)
    v2i r = __builtin_amdgcn_permlane32_swap(f2i(v), f2i(v), false, false);
    return i2f((lane & 32) ? r.x : r.y);
  }
}

// RY on a lane bit (MASK = 1<<bit)
template <int MASK>
__device__ __forceinline__ void ry_lane(float (&a)[8], float c, float s, int lane) {
  const float sgn = (lane & MASK) ? s : -s;
  float p[8];
  #pragma unroll
  for (int r = 0; r < 8; ++r) p[r] = shx<MASK>(a[r], lane);
  #pragma unroll
  for (int r = 0; r < 8; ++r) a[r] = c * a[r] + sgn * p[r];
}

// RY on a register bit RB
template <int RB>
__device__ __forceinline__ void ry_reg(float (&a)[8], float c, float s) {
  #pragma unroll
  for (int r = 0; r < 8; ++r) {
    if (!(r & (1 << RB))) {
      const int r1 = r | (1 << RB);
      const float a0 = a[r], a1 = a[r1];
      a[r]  = c * a0 - s * a1;
      a[r1] = s * a0 + c * a1;
    }
  }
}

// full 64-lane butterfly sum of N interleaved values (validated r4; mask16 now VALU)
template <int N>
__device__ __forceinline__ void red64(float (&v)[N], int lane) {
  #pragma unroll
  for (int w = 0; w < N; ++w) v[w] += shx<1>(v[w], lane);
  #pragma unroll
  for (int w = 0; w < N; ++w) v[w] += shx<2>(v[w], lane);
  #pragma unroll
  for (int w = 0; w < N; ++w) v[w] += shx<4>(v[w], lane);
  #pragma unroll
  for (int w = 0; w < N; ++w) v[w] += shx<8>(v[w], lane);
  #pragma unroll
  for (int w = 0; w < N; ++w) v[w] += shx<16>(v[w], lane);
  #pragma unroll
  for (int w = 0; w < N; ++w) v[w] += shx<32>(v[w], lane);
}

__global__ __launch_bounds__(64) void qst_kernel(
    const float* __restrict__ x,       // [32,54]
    const float* __restrict__ pre_w,   // [9,54]
    const float* __restrict__ pre_b,   // [9]
    const float* __restrict__ qp,      // [54] = [6,9]
    const float* __restrict__ post_w,  // [9,9]
    const float* __restrict__ post_b,  // [9]
    float* __restrict__ out)           // [32,9]
{
  const int b = blockIdx.x;
  const int lane = (int)threadIdx.x;  // one wave per batch element

  // ---- circuit-weight trig, lane-parallel: lane i holds cos/sin(qp[i]/2) ----
  const float qv = (lane < 54) ? qp[lane] : 0.0f;
  const float qc = __cosf(qv * 0.5f);
  const float qs = __sinf(qv * 0.5f);

  // ---- pre-layer: 9 interleaved 64-lane reductions ----
  const float xv = (lane < 54) ? x[b * 54 + lane] : 0.0f;
  float s9[NQ];
  #pragma unroll
  for (int w = 0; w < NQ; ++w) {
    const float pw = (lane < 54) ? pre_w[w * 54 + lane] : 0.0f;
    s9[w] = xv * pw;
  }
  red64<NQ>(s9, lane);
  float em[NQ], ep[NQ];   // c-s, c+s per wire (wave-uniform after butterfly)
  #pragma unroll
  for (int w = 0; w < NQ; ++w) {
    const float h = tanh_fast(s9[w] + pre_b[w]) * 0.78539816339744831f;  // theta/2
    const float c = __cosf(h), s = __sinf(h);
    em[w] = c - s;
    ep[w] = c + s;
  }

  // state: idx = lane*8 + r. wire w -> idx bit (8-w): w=0..5 -> lane bit (5-w); w=6,7,8 -> reg bit 2,1,0.
  // Input RY layer on the uniform H-state is SEPARABLE (validated r7):
  //   amp(idx) = 1/sqrt(512) * prod_w (bit_w ? (c_w+s_w) : (c_w-s_w))
  const float f0 = (lane & 32) ? ep[0] : em[0];
  const float f1 = (lane & 16) ? ep[1] : em[1];
  const float f2 = (lane &  8) ? ep[2] : em[2];
  const float f3 = (lane &  4) ? ep[3] : em[3];
  const float f4 = (lane &  2) ? ep[4] : em[4];
  const float f5 = (lane &  1) ? ep[5] : em[5];
  const float P  = 0.044194173824159216f * ((f0 * f1) * (f2 * f3)) * (f4 * f5);
  float a[8];
  #pragma unroll
  for (int r = 0; r < 8; ++r)
    a[r] = P * ((r & 4) ? ep[6] : em[6])
             * ((r & 2) ? ep[7] : em[7])
             * ((r & 1) ? ep[8] : em[8]);

  // ---- 6 depth iterations ----
  // Both CNOT layers fused into one gather: out[i] = in[T(i)], T linear over GF(2):
  //  srcLane = lane ^ ((lane>>1)&0x1F) ^ ((lane>>2)&0x05)   (same for all regs)
  //  srcReg  = s0(r) ^ (lane&1 ? 6 : 0), s0 = [0,1,3,2,6,7,5,4]
  const int srcLane = lane ^ ((lane >> 1) & 0x1F) ^ ((lane >> 2) & 0x05);
  #pragma unroll
  for (int k = 0; k < QD; ++k) {
    float u[8];
    #pragma unroll
    for (int r = 0; r < 8; ++r) u[r] = bperm_f(srcLane, a[r]);
    const bool L0 = lane & 1;
    a[0] = L0 ? u[6] : u[0];
    a[1] = L0 ? u[7] : u[1];
    a[2] = L0 ? u[5] : u[3];
    a[3] = L0 ? u[4] : u[2];
    a[4] = L0 ? u[0] : u[6];
    a[5] = L0 ? u[1] : u[7];
    a[6] = L0 ? u[3] : u[5];
    a[7] = L0 ? u[2] : u[4];

    // weight RY layer: broadcast cos/sin from lane k*9+w
    ry_lane<32>(a, rdlane_f(qc, k * NQ + 0), rdlane_f(qs, k * NQ + 0), lane);
    ry_lane<16>(a, rdlane_f(qc, k * NQ + 1), rdlane_f(qs, k * NQ + 1), lane);
    ry_lane< 8>(a, rdlane_f(qc, k * NQ + 2), rdlane_f(qs, k * NQ + 2), lane);
    ry_lane< 4>(a, rdlane_f(qc, k * NQ + 3), rdlane_f(qs, k * NQ + 3), lane);
    ry_lane< 2>(a, rdlane_f(qc, k * NQ + 4), rdlane_f(qs, k * NQ + 4), lane);
    ry_lane< 1>(a, rdlane_f(qc, k * NQ + 5), rdlane_f(qs, k * NQ + 5), lane);
    ry_reg<2>(a, rdlane_f(qc, k * NQ + 6), rdlane_f(qs, k * NQ + 6));
    ry_reg<1>(a, rdlane_f(qc, k * NQ + 7), rdlane_f(qs, k * NQ + 7));
    ry_reg<0>(a, rdlane_f(qc, k * NQ + 8), rdlane_f(qs, k * NQ + 8));
  }

  // ---- expectations <Z_w> ----
  float sq[8];
  #pragma unroll
  for (int r = 0; r < 8; ++r) sq[r] = a[r] * a[r];
  const float S  = ((sq[0] + sq[1]) + (sq[2] + sq[3])) + ((sq[4] + sq[5]) + (sq[6] + sq[7]));
  const float T2 = ((sq[0] + sq[1]) + (sq[2] + sq[3])) - ((sq[4] + sq[5]) + (sq[6] + sq[7]));
  const float T1 = ((sq[0] + sq[1]) + (sq[4] + sq[5])) - ((sq[2] + sq[3]) + (sq[6] + sq[7]));
  const float T0 = ((sq[0] + sq[2]) + (sq[4] + sq[6])) - ((sq[1] + sq[3]) + (sq[5] + sq[7]));

  float q[NQ];
  #pragma unroll
  for (int w = 0; w < 6; ++w)
    q[w] = ((lane >> (5 - w)) & 1) ? -S : S;
  q[6] = T2; q[7] = T1; q[8] = T0;

  red64<NQ>(q, lane);   // butterfly; total in every lane

  // ---- post layer ----
  if (lane < NQ) {
    float acc = post_b[lane];
    #pragma unroll
    for (int w = 0; w < NQ; ++w) acc += q[w] * post_w[lane * NQ + w];
    out[b * NQ + lane] = acc;
  }
}

extern "C" void kernel_launch(void* const* d_in, const int* in_sizes, int n_in,
                              void* d_out, int out_size, void* d_ws, size_t ws_size,
                              hipStream_t stream) {
  qst_kernel<<<NBATCH, 64, 0, stream>>>(
      (const float*)d_in[0], (const float*)d_in[1], (const float*)d_in[2],
      (const float*)d_in[3], (const float*)d_in[4], (const float*)d_in[5],
      (float*)d_out);
}